// Round 1
// baseline (548.254 us; speedup 1.0000x reference)
//
#include <hip/hip_runtime.h>

#define NN 10000
#define NE 160000
#define NG 512
#define DIN 128
#define DH 512
#define DOUT 16

// ---------------- degree / CSR build ----------------

__global__ void k_deg_count(const int* __restrict__ dst, int* __restrict__ deg) {
    int e = blockIdx.x * blockDim.x + threadIdx.x;
    if (e < NE) atomicAdd(&deg[dst[e]], 1);
}

__global__ void k_dinv(const int* __restrict__ deg, float* __restrict__ dinv) {
    int n = blockIdx.x * blockDim.x + threadIdx.x;
    if (n < NN) dinv[n] = rsqrtf((float)deg[n] + 1.0f);
}

__global__ __launch_bounds__(1024) void k_scan(const int* __restrict__ cnt, int* __restrict__ rowptr) {
    __shared__ int part[1024];
    int tid = threadIdx.x;
    const int PER = 10;  // 1024*10 >= 10000
    int base = tid * PER;
    int local[PER];
    int s = 0;
#pragma unroll
    for (int i = 0; i < PER; ++i) {
        int idx = base + i;
        int v = (idx < NN) ? cnt[idx] : 0;
        local[i] = s;
        s += v;
    }
    part[tid] = s;
    __syncthreads();
    for (int off = 1; off < 1024; off <<= 1) {
        int v = (tid >= off) ? part[tid - off] : 0;
        __syncthreads();
        part[tid] += v;
        __syncthreads();
    }
    int offset = (tid > 0) ? part[tid - 1] : 0;
#pragma unroll
    for (int i = 0; i < PER; ++i) {
        int idx = base + i;
        if (idx < NN) rowptr[idx] = offset + local[i];
    }
    if (tid == 1023) rowptr[NN] = part[1023];
}

__global__ void k_fill_csr(const int* __restrict__ src, const int* __restrict__ dst,
                           const float* __restrict__ dinv, const int* __restrict__ rowptr,
                           int* __restrict__ cursor, int* __restrict__ csr_src,
                           float* __restrict__ csr_coef) {
    int e = blockIdx.x * blockDim.x + threadIdx.x;
    if (e >= NE) return;
    int s = src[e], d = dst[e];
    int pos = atomicAdd(&cursor[d], 1);
    int idx = rowptr[d] + pos;
    csr_src[idx] = s;
    csr_coef[idx] = dinv[s] * dinv[d];
}

// ---------------- layernorm (one wave per row) ----------------

template <int D>
__global__ __launch_bounds__(256) void k_layernorm(const float* __restrict__ x,
                                                   const float* __restrict__ g,
                                                   const float* __restrict__ b,
                                                   float* __restrict__ y) {
    int row = blockIdx.x * 4 + (threadIdx.x >> 6);
    int lane = threadIdx.x & 63;
    if (row >= NN) return;
    const float* xr = x + (size_t)row * D;
    float s = 0.f, s2 = 0.f;
#pragma unroll
    for (int j = lane; j < D; j += 64) {
        float v = xr[j];
        s += v;
        s2 += v * v;
    }
#pragma unroll
    for (int off = 32; off; off >>= 1) {
        s += __shfl_down(s, off);
        s2 += __shfl_down(s2, off);
    }
    s = __shfl(s, 0);
    s2 = __shfl(s2, 0);
    float mu = s / (float)D;
    float var = s2 / (float)D - mu * mu;
    float r = rsqrtf(var + 1e-5f);
    float* yr = y + (size_t)row * D;
#pragma unroll
    for (int j = lane; j < D; j += 64) yr[j] = (xr[j] - mu) * r * g[j] + b[j];
}

// ---------------- fp32 tiled GEMM: C[M,512] = A[M,K] @ B[K,512] ----------------

__global__ __launch_bounds__(256) void k_gemm(const float* __restrict__ A,
                                              const float* __restrict__ B,
                                              float* __restrict__ C, int M, int K) {
    __shared__ float As[16][64 + 4];
    __shared__ float Bs[16][64 + 4];
    int bm = blockIdx.x * 64, bn = blockIdx.y * 64;
    int tid = threadIdx.x;
    int tm = tid >> 4, tn = tid & 15;
    float acc[4][4] = {};
    int am = tid >> 2;         // 0..63
    int ak = (tid & 3) * 4;    // 0,4,8,12
    int bk = tid >> 4;         // 0..15
    int bn0 = (tid & 15) * 4;  // 0..60
    for (int k0 = 0; k0 < K; k0 += 16) {
        float4 av = make_float4(0.f, 0.f, 0.f, 0.f);
        if (bm + am < M) av = *(const float4*)&A[(size_t)(bm + am) * K + k0 + ak];
        As[ak + 0][am] = av.x;
        As[ak + 1][am] = av.y;
        As[ak + 2][am] = av.z;
        As[ak + 3][am] = av.w;
        float4 bv = *(const float4*)&B[(size_t)(k0 + bk) * DH + bn + bn0];
        Bs[bk][bn0 + 0] = bv.x;
        Bs[bk][bn0 + 1] = bv.y;
        Bs[bk][bn0 + 2] = bv.z;
        Bs[bk][bn0 + 3] = bv.w;
        __syncthreads();
#pragma unroll
        for (int kk = 0; kk < 16; ++kk) {
            float a[4], b[4];
#pragma unroll
            for (int i = 0; i < 4; ++i) a[i] = As[kk][tm * 4 + i];
#pragma unroll
            for (int j = 0; j < 4; ++j) b[j] = Bs[kk][tn * 4 + j];
#pragma unroll
            for (int i = 0; i < 4; ++i)
#pragma unroll
                for (int j = 0; j < 4; ++j) acc[i][j] += a[i] * b[j];
        }
        __syncthreads();
    }
#pragma unroll
    for (int i = 0; i < 4; ++i) {
        int row = bm + tm * 4 + i;
        if (row < M) {
            float4 v = make_float4(acc[i][0], acc[i][1], acc[i][2], acc[i][3]);
            *(float4*)&C[(size_t)row * DH + bn + tn * 4] = v;
        }
    }
}

// ---------------- GCN aggregate (+bias +relu), one block per node ----------------

__global__ __launch_bounds__(256) void k_aggregate(const float* __restrict__ h,
                                                   const int* __restrict__ rowptr,
                                                   const int* __restrict__ csr_src,
                                                   const float* __restrict__ csr_coef,
                                                   const float* __restrict__ dinv,
                                                   const float* __restrict__ bias,
                                                   float* __restrict__ out) {
    int n = blockIdx.x;
    int t = threadIdx.x;
    int s0 = rowptr[n], s1 = rowptr[n + 1];
    float a0 = 0.f, a1 = 0.f;
    for (int k = s0; k < s1; ++k) {
        int s = csr_src[k];
        float c = csr_coef[k];
        a0 += h[(size_t)s * DH + t] * c;
        a1 += h[(size_t)s * DH + t + 256] * c;
    }
    float di = dinv[n];
    float sc = di * di;
    a0 += h[(size_t)n * DH + t] * sc;
    a1 += h[(size_t)n * DH + t + 256] * sc;
    a0 += bias[t];
    a1 += bias[t + 256];
    out[(size_t)n * DH + t] = fmaxf(a0, 0.f);
    out[(size_t)n * DH + t + 256] = fmaxf(a1, 0.f);
}

// ---------------- mean-pool by graph (batch sorted -> binary search) ----------------

__global__ __launch_bounds__(256) void k_pool(const float* __restrict__ h,
                                              const int* __restrict__ batch,
                                              float* __restrict__ pooled) {
    int g = blockIdx.x;
    int t = threadIdx.x;
    int lo = 0, hi = NN;
    while (lo < hi) {
        int mid = (lo + hi) >> 1;
        if (batch[mid] < g) lo = mid + 1;
        else hi = mid;
    }
    int start = lo;
    hi = NN;
    while (lo < hi) {
        int mid = (lo + hi) >> 1;
        if (batch[mid] < g + 1) lo = mid + 1;
        else hi = mid;
    }
    int end = lo;
    float a0 = 0.f, a1 = 0.f;
    for (int i = start; i < end; ++i) {
        a0 += h[(size_t)i * DH + t];
        a1 += h[(size_t)i * DH + t + 256];
    }
    float cnt = fmaxf((float)(end - start), 1.0f);
    pooled[g * DH + t] = a0 / cnt;
    pooled[g * DH + t + 256] = a1 / cnt;
}

// ---------------- final linear: out[G,16] = pooled[G,512] @ linW[512,16] + linb ----------------

__global__ __launch_bounds__(256) void k_final(const float* __restrict__ pooled,
                                               const float* __restrict__ linW,
                                               const float* __restrict__ linb,
                                               float* __restrict__ out) {
    __shared__ float red[256];
    int g = blockIdx.x;
    int t = threadIdx.x;
    int o = t & 15;
    int c = t >> 4;
    float s = 0.f;
    int k0 = c * 32;
    for (int k = k0; k < k0 + 32; ++k) s += pooled[g * DH + k] * linW[k * DOUT + o];
    red[t] = s;
    __syncthreads();
    if (t < DOUT) {
        float acc = 0.f;
        for (int cc = 0; cc < 16; ++cc) acc += red[cc * 16 + t];
        out[g * DOUT + t] = acc + linb[t];
    }
}

// ---------------- launch ----------------

extern "C" void kernel_launch(void* const* d_in, const int* in_sizes, int n_in,
                              void* d_out, int out_size, void* d_ws, size_t ws_size,
                              hipStream_t stream) {
    const float* x = (const float*)d_in[0];
    const int* ei = (const int*)d_in[1];
    const int* batch = (const int*)d_in[2];
    const float* W0 = (const float*)d_in[3];
    const float* b0 = (const float*)d_in[4];
    const float* g0 = (const float*)d_in[5];
    const float* be0 = (const float*)d_in[6];
    const float* Wh = (const float*)d_in[7];
    const float* bh = (const float*)d_in[8];
    const float* gh = (const float*)d_in[9];
    const float* beh = (const float*)d_in[10];
    const float* linW = (const float*)d_in[11];
    const float* linb = (const float*)d_in[12];
    float* out = (float*)d_out;

    // workspace layout (all fp32 unless noted); total ~64 MB
    float* bufA = (float*)d_ws;                  // N*512  (layer output h)
    float* bufB = bufA + (size_t)NN * DH;        // N*512  (layernorm output)
    float* bufC = bufB + (size_t)NN * DH;        // N*512  (gemm output)
    float* pooled = bufC + (size_t)NN * DH;      // G*512
    float* dinv = pooled + (size_t)NG * DH;      // N
    int* deg = (int*)(dinv + NN);                // N
    int* rowptr = deg + NN;                      // N+1
    int* cursor = rowptr + NN + 1;               // N
    int* csr_src = cursor + NN;                  // E
    float* csr_coef = (float*)(csr_src + NE);    // E

    const int* srcp = ei;
    const int* dstp = ei + NE;

    hipMemsetAsync(deg, 0, NN * sizeof(int), stream);
    hipMemsetAsync(cursor, 0, NN * sizeof(int), stream);
    k_deg_count<<<(NE + 255) / 256, 256, 0, stream>>>(dstp, deg);
    k_dinv<<<(NN + 255) / 256, 256, 0, stream>>>(deg, dinv);
    k_scan<<<1, 1024, 0, stream>>>(deg, rowptr);
    k_fill_csr<<<(NE + 255) / 256, 256, 0, stream>>>(srcp, dstp, dinv, rowptr, cursor,
                                                     csr_src, csr_coef);

    dim3 gemm_grid((NN + 63) / 64, DH / 64);

    // layer 0: LN(x) -> GEMM(128->512) -> aggregate(+b0, relu)
    k_layernorm<DIN><<<(NN + 3) / 4, 256, 0, stream>>>(x, g0, be0, bufB);
    k_gemm<<<gemm_grid, 256, 0, stream>>>(bufB, W0, bufC, NN, DIN);
    k_aggregate<<<NN, 256, 0, stream>>>(bufC, rowptr, csr_src, csr_coef, dinv, b0, bufA);

    // layers 1..3
    for (int l = 0; l < 3; ++l) {
        k_layernorm<DH><<<(NN + 3) / 4, 256, 0, stream>>>(bufA, gh + l * DH, beh + l * DH, bufB);
        k_gemm<<<gemm_grid, 256, 0, stream>>>(bufB, Wh + (size_t)l * DH * DH, bufC, NN, DH);
        k_aggregate<<<NN, 256, 0, stream>>>(bufC, rowptr, csr_src, csr_coef, dinv,
                                            bh + l * DH, bufA);
    }

    k_pool<<<NG, 256, 0, stream>>>(bufA, batch, pooled);
    k_final<<<NG, 256, 0, stream>>>(pooled, linW, linb, out);
}

// Round 2
// 315.361 us; speedup vs baseline: 1.7385x; 1.7385x over previous
//
#include <hip/hip_runtime.h>

#define NN 10000
#define NE 160000
#define NG 512
#define DIN 128
#define DH 512
#define DOUT 16
#define NPAD 10112   // 79 * 128 (GEMM M-tile padding)

typedef __bf16 bf16_t;
typedef __attribute__((ext_vector_type(8))) __bf16 bf16x8;
typedef __attribute__((ext_vector_type(2))) __bf16 bf16x2;
typedef __attribute__((ext_vector_type(4))) float f32x4;

// ---------------- degree / CSR build ----------------

__global__ void k_deg_count(const int* __restrict__ dst, int* __restrict__ deg) {
    int e = blockIdx.x * blockDim.x + threadIdx.x;
    if (e < NE) atomicAdd(&deg[dst[e]], 1);
}

__global__ void k_dinv(const int* __restrict__ deg, float* __restrict__ dinv) {
    int n = blockIdx.x * blockDim.x + threadIdx.x;
    if (n < NN) dinv[n] = rsqrtf((float)deg[n] + 1.0f);
}

__global__ __launch_bounds__(1024) void k_scan(const int* __restrict__ cnt, int* __restrict__ rowptr) {
    __shared__ int part[1024];
    int tid = threadIdx.x;
    const int PER = 10;
    int base = tid * PER;
    int local[PER];
    int s = 0;
#pragma unroll
    for (int i = 0; i < PER; ++i) {
        int idx = base + i;
        int v = (idx < NN) ? cnt[idx] : 0;
        local[i] = s;
        s += v;
    }
    part[tid] = s;
    __syncthreads();
    for (int off = 1; off < 1024; off <<= 1) {
        int v = (tid >= off) ? part[tid - off] : 0;
        __syncthreads();
        part[tid] += v;
        __syncthreads();
    }
    int offset = (tid > 0) ? part[tid - 1] : 0;
#pragma unroll
    for (int i = 0; i < PER; ++i) {
        int idx = base + i;
        if (idx < NN) rowptr[idx] = offset + local[i];
    }
    if (tid == 1023) rowptr[NN] = part[1023];
}

__global__ void k_fill_csr(const int* __restrict__ src, const int* __restrict__ dst,
                           const float* __restrict__ dinv, const int* __restrict__ rowptr,
                           int* __restrict__ cursor, int* __restrict__ csr_src,
                           float* __restrict__ csr_coef) {
    int e = blockIdx.x * blockDim.x + threadIdx.x;
    if (e >= NE) return;
    int s = src[e], d = dst[e];
    int pos = atomicAdd(&cursor[d], 1);
    int idx = rowptr[d] + pos;
    csr_src[idx] = s;
    csr_coef[idx] = dinv[s] * dinv[d];
}

// ---------------- weight transpose + bf16 convert: Wt[n][k] = W[k][n] ----------------

__global__ void k_wt(const float* __restrict__ W, bf16_t* __restrict__ Wt, int K) {
    int idx = blockIdx.x * 256 + threadIdx.x;
    if (idx >= K * 512) return;
    int k = idx >> 9, n = idx & 511;
    Wt[(size_t)n * K + k] = (bf16_t)W[idx];
}

// ---------------- layer-0 layernorm: x fp32 [NN][128] -> bf16 ----------------

__global__ __launch_bounds__(256) void k_ln0(const float* __restrict__ x,
                                             const float* __restrict__ g,
                                             const float* __restrict__ b,
                                             bf16_t* __restrict__ y) {
    int row = blockIdx.x * 4 + (threadIdx.x >> 6);
    int lane = threadIdx.x & 63;
    if (row >= NN) return;
    const float* xr = x + (size_t)row * DIN;
    float v0 = xr[lane], v1 = xr[lane + 64];
    float s = v0 + v1, s2 = v0 * v0 + v1 * v1;
#pragma unroll
    for (int off = 32; off; off >>= 1) {
        s += __shfl_xor(s, off);
        s2 += __shfl_xor(s2, off);
    }
    float mu = s * (1.f / 128.f);
    float var = s2 * (1.f / 128.f) - mu * mu;
    float r = rsqrtf(var + 1e-5f);
    bf16_t* yr = y + (size_t)row * DIN;
    yr[lane] = (bf16_t)((v0 - mu) * r * g[lane] + b[lane]);
    yr[lane + 64] = (bf16_t)((v1 - mu) * r * g[lane + 64] + b[lane + 64]);
}

// ---------------- bf16 MFMA GEMM: C[NPAD][512] = A[NPAD][K] @ Wt^T ----------------
// Wt is [512][K] (row n holds W[:,n]); BM=128 BN=64 BK=64, 4 waves each 64x32.
// LDS tiles use XOR chunk swizzle (chunk ^= row&7) with pre-swizzled global source.

__global__ __launch_bounds__(256) void k_gemm_bf16(const bf16_t* __restrict__ A,
                                                   const bf16_t* __restrict__ Bt,
                                                   bf16_t* __restrict__ C, int K) {
    __shared__ bf16_t As[128 * 64];
    __shared__ bf16_t Bs[64 * 64];
    int tid = threadIdx.x;
    int lane = tid & 63, w = tid >> 6;
    int row0 = blockIdx.x * 128;
    int col0 = blockIdx.y * 64;
    int wm = w >> 1, wn = w & 1;  // wave computes 64x32 at (wm*64, wn*32)

    f32x4 acc[4][2];
#pragma unroll
    for (int i = 0; i < 4; ++i)
#pragma unroll
        for (int j = 0; j < 2; ++j) acc[i][j] = (f32x4){0.f, 0.f, 0.f, 0.f};

    int lr = lane >> 3;        // 0..7 (row within 8-row issue group)
    int lc = lane & 7;         // chunk slot

    for (int kt = 0; kt < K; kt += 64) {
        // stage A: 128 rows x 64 cols bf16 (16KB); 4 issues/wave of 1KB
#pragma unroll
        for (int i = 0; i < 4; ++i) {
            int r = w * 32 + i * 8 + lr;
            int cg = lc ^ (r & 7);  // pre-swizzled global chunk
            const bf16_t* src = A + (size_t)(row0 + r) * K + kt + cg * 8;
            __builtin_amdgcn_global_load_lds(
                (const __attribute__((address_space(1))) void*)src,
                (__attribute__((address_space(3))) void*)(As + (w * 32 + i * 8) * 64),
                16, 0, 0);
        }
        // stage B: 64 rows x 64 cols (8KB); 2 issues/wave
#pragma unroll
        for (int i = 0; i < 2; ++i) {
            int r = w * 16 + i * 8 + lr;
            int cg = lc ^ (r & 7);
            const bf16_t* src = Bt + (size_t)(col0 + r) * K + kt + cg * 8;
            __builtin_amdgcn_global_load_lds(
                (const __attribute__((address_space(1))) void*)src,
                (__attribute__((address_space(3))) void*)(Bs + (w * 16 + i * 8) * 64),
                16, 0, 0);
        }
        __syncthreads();
#pragma unroll
        for (int ks = 0; ks < 2; ++ks) {
            bf16x8 af[4], bfr[2];
#pragma unroll
            for (int mi = 0; mi < 4; ++mi) {
                int mr = wm * 64 + mi * 16 + (lane & 15);
                int c = (ks * 4 + (lane >> 4)) ^ (mr & 7);
                af[mi] = *(const bf16x8*)&As[mr * 64 + c * 8];
            }
#pragma unroll
            for (int ni = 0; ni < 2; ++ni) {
                int nr = wn * 32 + ni * 16 + (lane & 15);
                int c = (ks * 4 + (lane >> 4)) ^ (nr & 7);
                bfr[ni] = *(const bf16x8*)&Bs[nr * 64 + c * 8];
            }
#pragma unroll
            for (int mi = 0; mi < 4; ++mi)
#pragma unroll
                for (int ni = 0; ni < 2; ++ni)
                    acc[mi][ni] = __builtin_amdgcn_mfma_f32_16x16x32_bf16(
                        af[mi], bfr[ni], acc[mi][ni], 0, 0, 0);
        }
        __syncthreads();
    }
    // C/D layout: col = lane&15, row = (lane>>4)*4 + q
#pragma unroll
    for (int mi = 0; mi < 4; ++mi)
#pragma unroll
        for (int ni = 0; ni < 2; ++ni) {
            int col = col0 + wn * 32 + ni * 16 + (lane & 15);
#pragma unroll
            for (int q = 0; q < 4; ++q) {
                int row = row0 + wm * 64 + mi * 16 + (lane >> 4) * 4 + q;
                C[(size_t)row * DH + col] = (bf16_t)acc[mi][ni][q];
            }
        }
}

// ---------------- fused aggregate + bias + relu (+ layernorm -> bf16) ----------------

template <bool DO_LN>
__global__ __launch_bounds__(256) void k_agg(const bf16_t* __restrict__ H,
                                             const int* __restrict__ rowptr,
                                             const int* __restrict__ csr_src,
                                             const float* __restrict__ csr_coef,
                                             const float* __restrict__ dinv,
                                             const float* __restrict__ bias,
                                             const float* __restrict__ gamma,
                                             const float* __restrict__ beta,
                                             bf16_t* __restrict__ out_bf,
                                             float* __restrict__ out_f) {
    int n = blockIdx.x, t = threadIdx.x;
    int c0 = t * 2;
    float a0 = 0.f, a1 = 0.f;
    int s0 = rowptr[n], s1 = rowptr[n + 1];
    for (int k = s0; k < s1; ++k) {
        int s = csr_src[k];
        float cf = csr_coef[k];
        bf16x2 v = *(const bf16x2*)&H[(size_t)s * DH + c0];
        a0 += (float)v[0] * cf;
        a1 += (float)v[1] * cf;
    }
    float di = dinv[n];
    float sc = di * di;
    bf16x2 vs = *(const bf16x2*)&H[(size_t)n * DH + c0];
    a0 += (float)vs[0] * sc;
    a1 += (float)vs[1] * sc;
    a0 = fmaxf(a0 + bias[c0], 0.f);
    a1 = fmaxf(a1 + bias[c0 + 1], 0.f);
    if (DO_LN) {
        float s = a0 + a1, s2 = a0 * a0 + a1 * a1;
#pragma unroll
        for (int off = 32; off; off >>= 1) {
            s += __shfl_xor(s, off);
            s2 += __shfl_xor(s2, off);
        }
        __shared__ float rs[8];
        int w = t >> 6, lane = t & 63;
        if (lane == 0) {
            rs[w] = s;
            rs[4 + w] = s2;
        }
        __syncthreads();
        s = rs[0] + rs[1] + rs[2] + rs[3];
        s2 = rs[4] + rs[5] + rs[6] + rs[7];
        float mu = s * (1.f / 512.f);
        float var = s2 * (1.f / 512.f) - mu * mu;
        float r = rsqrtf(var + 1e-5f);
        bf16x2 o;
        o[0] = (bf16_t)((a0 - mu) * r * gamma[c0] + beta[c0]);
        o[1] = (bf16_t)((a1 - mu) * r * gamma[c0 + 1] + beta[c0 + 1]);
        *(bf16x2*)&out_bf[(size_t)n * DH + c0] = o;
    } else {
        out_f[(size_t)n * DH + c0] = a0;
        out_f[(size_t)n * DH + c0 + 1] = a1;
    }
}

// ---------------- mean-pool by graph ----------------

__global__ __launch_bounds__(256) void k_pool(const float* __restrict__ h,
                                              const int* __restrict__ batch,
                                              float* __restrict__ pooled) {
    int g = blockIdx.x;
    int t = threadIdx.x;
    int lo = 0, hi = NN;
    while (lo < hi) {
        int mid = (lo + hi) >> 1;
        if (batch[mid] < g) lo = mid + 1;
        else hi = mid;
    }
    int start = lo;
    hi = NN;
    while (lo < hi) {
        int mid = (lo + hi) >> 1;
        if (batch[mid] < g + 1) lo = mid + 1;
        else hi = mid;
    }
    int end = lo;
    float a0 = 0.f, a1 = 0.f;
    for (int i = start; i < end; ++i) {
        a0 += h[(size_t)i * DH + t];
        a1 += h[(size_t)i * DH + t + 256];
    }
    float cnt = fmaxf((float)(end - start), 1.0f);
    pooled[g * DH + t] = a0 / cnt;
    pooled[g * DH + t + 256] = a1 / cnt;
}

// ---------------- final linear ----------------

__global__ __launch_bounds__(256) void k_final(const float* __restrict__ pooled,
                                               const float* __restrict__ linW,
                                               const float* __restrict__ linb,
                                               float* __restrict__ out) {
    __shared__ float red[256];
    int g = blockIdx.x;
    int t = threadIdx.x;
    int o = t & 15;
    int c = t >> 4;
    float s = 0.f;
    int k0 = c * 32;
    for (int k = k0; k < k0 + 32; ++k) s += pooled[g * DH + k] * linW[k * DOUT + o];
    red[t] = s;
    __syncthreads();
    if (t < DOUT) {
        float acc = 0.f;
        for (int cc = 0; cc < 16; ++cc) acc += red[cc * 16 + t];
        out[g * DOUT + t] = acc + linb[t];
    }
}

// ---------------- launch ----------------

extern "C" void kernel_launch(void* const* d_in, const int* in_sizes, int n_in,
                              void* d_out, int out_size, void* d_ws, size_t ws_size,
                              hipStream_t stream) {
    const float* x = (const float*)d_in[0];
    const int* ei = (const int*)d_in[1];
    const int* batch = (const int*)d_in[2];
    const float* W0 = (const float*)d_in[3];
    const float* b0 = (const float*)d_in[4];
    const float* g0 = (const float*)d_in[5];
    const float* be0 = (const float*)d_in[6];
    const float* Wh = (const float*)d_in[7];
    const float* bh = (const float*)d_in[8];
    const float* gh = (const float*)d_in[9];
    const float* beh = (const float*)d_in[10];
    const float* linW = (const float*)d_in[11];
    const float* linb = (const float*)d_in[12];
    float* out = (float*)d_out;

    // workspace layout
    bf16_t* lnbuf = (bf16_t*)d_ws;                        // NPAD*512 bf16
    bf16_t* Cbf = lnbuf + (size_t)NPAD * DH;              // NPAD*512 bf16
    bf16_t* Wt0 = Cbf + (size_t)NPAD * DH;                // 512*128
    bf16_t* Wth = Wt0 + 512 * DIN;                        // 3*512*512
    float* hfin = (float*)(Wth + 3 * 512 * 512);          // NN*512 fp32
    float* pooled = hfin + (size_t)NN * DH;               // G*512
    float* dinv = pooled + (size_t)NG * DH;               // N
    int* deg = (int*)(dinv + NN);
    int* rowptr = deg + NN;
    int* cursor = rowptr + NN + 1;
    int* csr_src = cursor + NN;
    float* csr_coef = (float*)(csr_src + NE);

    const int* srcp = ei;
    const int* dstp = ei + NE;

    hipMemsetAsync(deg, 0, NN * sizeof(int), stream);
    hipMemsetAsync(cursor, 0, NN * sizeof(int), stream);
    k_deg_count<<<(NE + 255) / 256, 256, 0, stream>>>(dstp, deg);
    k_dinv<<<(NN + 255) / 256, 256, 0, stream>>>(deg, dinv);
    k_scan<<<1, 1024, 0, stream>>>(deg, rowptr);
    k_fill_csr<<<(NE + 255) / 256, 256, 0, stream>>>(srcp, dstp, dinv, rowptr, cursor,
                                                     csr_src, csr_coef);

    // weights -> bf16 transposed
    k_wt<<<(DIN * 512 + 255) / 256, 256, 0, stream>>>(W0, Wt0, DIN);
    for (int l = 0; l < 3; ++l)
        k_wt<<<(DH * 512 + 255) / 256, 256, 0, stream>>>(Wh + (size_t)l * DH * DH,
                                                         Wth + (size_t)l * DH * DH, DH);

    dim3 gemm_grid(NPAD / 128, DH / 64);

    // layer 0
    k_ln0<<<(NN + 3) / 4, 256, 0, stream>>>(x, g0, be0, lnbuf);
    k_gemm_bf16<<<gemm_grid, 256, 0, stream>>>(lnbuf, Wt0, Cbf, DIN);
    k_agg<true><<<NN, 256, 0, stream>>>(Cbf, rowptr, csr_src, csr_coef, dinv, b0,
                                        gh + 0 * DH, beh + 0 * DH, lnbuf, nullptr);
    // layers 1..2 (fused LN for next layer)
    for (int l = 0; l < 2; ++l) {
        k_gemm_bf16<<<gemm_grid, 256, 0, stream>>>(lnbuf, Wth + (size_t)l * DH * DH, Cbf, DH);
        k_agg<true><<<NN, 256, 0, stream>>>(Cbf, rowptr, csr_src, csr_coef, dinv,
                                            bh + l * DH, gh + (l + 1) * DH,
                                            beh + (l + 1) * DH, lnbuf, nullptr);
    }
    // layer 3 (no LN, fp32 out for pooling)
    k_gemm_bf16<<<gemm_grid, 256, 0, stream>>>(lnbuf, Wth + (size_t)2 * DH * DH, Cbf, DH);
    k_agg<false><<<NN, 256, 0, stream>>>(Cbf, rowptr, csr_src, csr_coef, dinv,
                                         bh + 2 * DH, nullptr, nullptr, nullptr, hfin);

    k_pool<<<NG, 256, 0, stream>>>(hfin, batch, pooled);
    k_final<<<NG, 256, 0, stream>>>(pooled, linW, linb, out);
}

// Round 3
// 235.363 us; speedup vs baseline: 2.3294x; 1.3399x over previous
//
#include <hip/hip_runtime.h>

#define NN 10000
#define NE 160000
#define NG 512
#define DIN 128
#define DH 512
#define DOUT 16
#define NPAD 10112   // 79 * 128 (GEMM M-tile padding)

typedef __bf16 bf16_t;
typedef __attribute__((ext_vector_type(8))) __bf16 bf16x8;
typedef __attribute__((ext_vector_type(2))) __bf16 bf16x2;
typedef __attribute__((ext_vector_type(4))) float f32x4;

// ---------------- degree / CSR build ----------------

__global__ void k_deg_count(const int* __restrict__ dst, int* __restrict__ deg) {
    int e = blockIdx.x * blockDim.x + threadIdx.x;
    if (e < NE) atomicAdd(&deg[dst[e]], 1);
}

__global__ void k_dinv(const int* __restrict__ deg, float* __restrict__ dinv) {
    int n = blockIdx.x * blockDim.x + threadIdx.x;
    if (n < NN) dinv[n] = rsqrtf((float)deg[n] + 1.0f);
}

__global__ __launch_bounds__(1024) void k_scan(const int* __restrict__ cnt, int* __restrict__ rowptr) {
    __shared__ int part[1024];
    int tid = threadIdx.x;
    const int PER = 10;
    int base = tid * PER;
    int local[PER];
    int s = 0;
#pragma unroll
    for (int i = 0; i < PER; ++i) {
        int idx = base + i;
        int v = (idx < NN) ? cnt[idx] : 0;
        local[i] = s;
        s += v;
    }
    part[tid] = s;
    __syncthreads();
    for (int off = 1; off < 1024; off <<= 1) {
        int v = (tid >= off) ? part[tid - off] : 0;
        __syncthreads();
        part[tid] += v;
        __syncthreads();
    }
    int offset = (tid > 0) ? part[tid - 1] : 0;
#pragma unroll
    for (int i = 0; i < PER; ++i) {
        int idx = base + i;
        if (idx < NN) rowptr[idx] = offset + local[i];
    }
    if (tid == 1023) rowptr[NN] = part[1023];
}

__global__ void k_fill_csr(const int* __restrict__ src, const int* __restrict__ dst,
                           const float* __restrict__ dinv, const int* __restrict__ rowptr,
                           int* __restrict__ cursor, int* __restrict__ csr_src,
                           float* __restrict__ csr_coef) {
    int e = blockIdx.x * blockDim.x + threadIdx.x;
    if (e >= NE) return;
    int s = src[e], d = dst[e];
    int pos = atomicAdd(&cursor[d], 1);
    int idx = rowptr[d] + pos;
    csr_src[idx] = s;
    csr_coef[idx] = dinv[s] * dinv[d];
}

// ---------------- all weights -> bf16 transposed in one launch ----------------

__global__ void k_wt_all(const float* __restrict__ W0, const float* __restrict__ Wh,
                         bf16_t* __restrict__ Wt0, bf16_t* __restrict__ Wth) {
    int idx = blockIdx.x * 256 + threadIdx.x;
    if (idx < 512 * DIN) {
        int k = idx >> 9, n = idx & 511;          // W0 is [128][512]
        Wt0[n * DIN + k] = (bf16_t)W0[idx];
    }
    int j = idx - 512 * DIN;
    if (j >= 0 && j < 3 * DH * DH) {
        int l = j / (DH * DH), r = j % (DH * DH);
        int k = r >> 9, n = r & 511;              // Wh[l] is [512][512]
        Wth[(size_t)l * DH * DH + n * DH + k] = (bf16_t)Wh[j];
    }
}

// ---------------- layer-0 layernorm: x fp32 [NN][128] -> bf16 ----------------

__global__ __launch_bounds__(256) void k_ln0(const float* __restrict__ x,
                                             const float* __restrict__ g,
                                             const float* __restrict__ b,
                                             bf16_t* __restrict__ y) {
    int row = blockIdx.x * 4 + (threadIdx.x >> 6);
    int lane = threadIdx.x & 63;
    if (row >= NN) return;
    const float* xr = x + (size_t)row * DIN;
    float v0 = xr[lane], v1 = xr[lane + 64];
    float s = v0 + v1, s2 = v0 * v0 + v1 * v1;
#pragma unroll
    for (int off = 32; off; off >>= 1) {
        s += __shfl_xor(s, off);
        s2 += __shfl_xor(s2, off);
    }
    float mu = s * (1.f / 128.f);
    float var = s2 * (1.f / 128.f) - mu * mu;
    float r = rsqrtf(var + 1e-5f);
    bf16_t* yr = y + (size_t)row * DIN;
    yr[lane] = (bf16_t)((v0 - mu) * r * g[lane] + b[lane]);
    yr[lane + 64] = (bf16_t)((v1 - mu) * r * g[lane + 64] + b[lane + 64]);
}

// ---------------- standalone layernorm 512-wide bf16 -> bf16 ----------------

__global__ __launch_bounds__(256) void k_ln512(const bf16_t* __restrict__ x,
                                               const float* __restrict__ g,
                                               const float* __restrict__ b,
                                               bf16_t* __restrict__ y) {
    int row = blockIdx.x * 4 + (threadIdx.x >> 6);
    int lane = threadIdx.x & 63;
    if (row >= NN) return;
    int c0 = lane * 8;
    bf16x8 v = *(const bf16x8*)&x[(size_t)row * DH + c0];
    float f[8];
    float s = 0.f, s2 = 0.f;
#pragma unroll
    for (int i = 0; i < 8; ++i) {
        f[i] = (float)v[i];
        s += f[i];
        s2 += f[i] * f[i];
    }
#pragma unroll
    for (int off = 32; off; off >>= 1) {
        s += __shfl_xor(s, off);
        s2 += __shfl_xor(s2, off);
    }
    float mu = s * (1.f / 512.f);
    float var = s2 * (1.f / 512.f) - mu * mu;
    float r = rsqrtf(var + 1e-5f);
    f32x4 g0 = *(const f32x4*)&g[c0], g1 = *(const f32x4*)&g[c0 + 4];
    f32x4 b0 = *(const f32x4*)&b[c0], b1 = *(const f32x4*)&b[c0 + 4];
    bf16x8 o;
#pragma unroll
    for (int i = 0; i < 4; ++i) {
        o[i] = (bf16_t)((f[i] - mu) * r * g0[i] + b0[i]);
        o[i + 4] = (bf16_t)((f[i + 4] - mu) * r * g1[i] + b1[i]);
    }
    *(bf16x8*)&y[(size_t)row * DH + c0] = o;
}

// ---------------- bf16 MFMA GEMM: C[NPAD][512] = A[NPAD][K] @ Wt^T ----------------
// Wt is [512][K]; BM=128 BN=64 BK=64, 4 waves each 64x32.
// LDS XOR chunk swizzle (chunk ^= row&7) with pre-swizzled global source.
// EPI: C = relu(acc + bias[col]) for layer-0 (agg-first ordering).

template <bool EPI>
__global__ __launch_bounds__(256) void k_gemm_bf16(const bf16_t* __restrict__ A,
                                                   const bf16_t* __restrict__ Bt,
                                                   const float* __restrict__ bias,
                                                   bf16_t* __restrict__ C, int K) {
    __shared__ bf16_t As[128 * 64];
    __shared__ bf16_t Bs[64 * 64];
    int tid = threadIdx.x;
    int lane = tid & 63, w = tid >> 6;
    int row0 = blockIdx.x * 128;
    int col0 = blockIdx.y * 64;
    int wm = w >> 1, wn = w & 1;

    f32x4 acc[4][2];
#pragma unroll
    for (int i = 0; i < 4; ++i)
#pragma unroll
        for (int j = 0; j < 2; ++j) acc[i][j] = (f32x4){0.f, 0.f, 0.f, 0.f};

    int lr = lane >> 3;
    int lc = lane & 7;

    for (int kt = 0; kt < K; kt += 64) {
#pragma unroll
        for (int i = 0; i < 4; ++i) {
            int r = w * 32 + i * 8 + lr;
            int cg = lc ^ (r & 7);
            const bf16_t* src = A + (size_t)(row0 + r) * K + kt + cg * 8;
            __builtin_amdgcn_global_load_lds(
                (const __attribute__((address_space(1))) void*)src,
                (__attribute__((address_space(3))) void*)(As + (w * 32 + i * 8) * 64),
                16, 0, 0);
        }
#pragma unroll
        for (int i = 0; i < 2; ++i) {
            int r = w * 16 + i * 8 + lr;
            int cg = lc ^ (r & 7);
            const bf16_t* src = Bt + (size_t)(col0 + r) * K + kt + cg * 8;
            __builtin_amdgcn_global_load_lds(
                (const __attribute__((address_space(1))) void*)src,
                (__attribute__((address_space(3))) void*)(Bs + (w * 16 + i * 8) * 64),
                16, 0, 0);
        }
        __syncthreads();
#pragma unroll
        for (int ks = 0; ks < 2; ++ks) {
            bf16x8 af[4], bfr[2];
#pragma unroll
            for (int mi = 0; mi < 4; ++mi) {
                int mr = wm * 64 + mi * 16 + (lane & 15);
                int c = (ks * 4 + (lane >> 4)) ^ (mr & 7);
                af[mi] = *(const bf16x8*)&As[mr * 64 + c * 8];
            }
#pragma unroll
            for (int ni = 0; ni < 2; ++ni) {
                int nr = wn * 32 + ni * 16 + (lane & 15);
                int c = (ks * 4 + (lane >> 4)) ^ (nr & 7);
                bfr[ni] = *(const bf16x8*)&Bs[nr * 64 + c * 8];
            }
#pragma unroll
            for (int mi = 0; mi < 4; ++mi)
#pragma unroll
                for (int ni = 0; ni < 2; ++ni)
                    acc[mi][ni] = __builtin_amdgcn_mfma_f32_16x16x32_bf16(
                        af[mi], bfr[ni], acc[mi][ni], 0, 0, 0);
        }
        __syncthreads();
    }
#pragma unroll
    for (int mi = 0; mi < 4; ++mi)
#pragma unroll
        for (int ni = 0; ni < 2; ++ni) {
            int col = col0 + wn * 32 + ni * 16 + (lane & 15);
            float bv = EPI ? bias[col] : 0.f;
#pragma unroll
            for (int q = 0; q < 4; ++q) {
                int row = row0 + wm * 64 + mi * 16 + (lane >> 4) * 4 + q;
                float v = acc[mi][ni][q];
                if (EPI) v = fmaxf(v + bv, 0.f);
                C[(size_t)row * DH + col] = (bf16_t)v;
            }
        }
}

// ---------------- layer-0 aggregate on 128-wide LN output (no bias/relu) ----------------

__global__ __launch_bounds__(256) void k_agg128(const bf16_t* __restrict__ H,
                                                const int* __restrict__ rowptr,
                                                const int* __restrict__ csr_src,
                                                const float* __restrict__ csr_coef,
                                                const float* __restrict__ dinv,
                                                bf16_t* __restrict__ out) {
    int w = threadIdx.x >> 6, lane = threadIdx.x & 63;
    int n = blockIdx.x * 4 + w;
    int c0 = lane * 2;
    float a0 = 0.f, a1 = 0.f;
    int s0 = rowptr[n], s1 = rowptr[n + 1];
    int k = s0;
    for (; k + 2 <= s1; k += 2) {
        int sA = csr_src[k], sB = csr_src[k + 1];
        float cA = csr_coef[k], cB = csr_coef[k + 1];
        bf16x2 vA = *(const bf16x2*)&H[(size_t)sA * DIN + c0];
        bf16x2 vB = *(const bf16x2*)&H[(size_t)sB * DIN + c0];
        a0 += (float)vA[0] * cA + (float)vB[0] * cB;
        a1 += (float)vA[1] * cA + (float)vB[1] * cB;
    }
    if (k < s1) {
        int sA = csr_src[k];
        float cA = csr_coef[k];
        bf16x2 vA = *(const bf16x2*)&H[(size_t)sA * DIN + c0];
        a0 += (float)vA[0] * cA;
        a1 += (float)vA[1] * cA;
    }
    float di = dinv[n], sc = di * di;
    bf16x2 vs = *(const bf16x2*)&H[(size_t)n * DIN + c0];
    a0 += (float)vs[0] * sc;
    a1 += (float)vs[1] * sc;
    bf16x2 o;
    o[0] = (bf16_t)a0;
    o[1] = (bf16_t)a1;
    *(bf16x2*)&out[(size_t)n * DIN + c0] = o;
}

// ---------------- fused aggregate + bias + relu (+ optional layernorm), wave per node ----------------

template <bool DO_LN>
__global__ __launch_bounds__(256) void k_agg(const bf16_t* __restrict__ H,
                                             const int* __restrict__ rowptr,
                                             const int* __restrict__ csr_src,
                                             const float* __restrict__ csr_coef,
                                             const float* __restrict__ dinv,
                                             const float* __restrict__ bias,
                                             const float* __restrict__ gamma,
                                             const float* __restrict__ beta,
                                             bf16_t* __restrict__ out) {
    int w = threadIdx.x >> 6, lane = threadIdx.x & 63;
    int n = blockIdx.x * 4 + w;
    int c0 = lane * 8;
    float acc[8] = {0.f, 0.f, 0.f, 0.f, 0.f, 0.f, 0.f, 0.f};
    int s0 = rowptr[n], s1 = rowptr[n + 1];
    int k = s0;
    for (; k + 2 <= s1; k += 2) {
        int sA = csr_src[k], sB = csr_src[k + 1];
        float cA = csr_coef[k], cB = csr_coef[k + 1];
        bf16x8 vA = *(const bf16x8*)&H[(size_t)sA * DH + c0];
        bf16x8 vB = *(const bf16x8*)&H[(size_t)sB * DH + c0];
#pragma unroll
        for (int i = 0; i < 8; ++i) acc[i] += (float)vA[i] * cA + (float)vB[i] * cB;
    }
    if (k < s1) {
        int sA = csr_src[k];
        float cA = csr_coef[k];
        bf16x8 vA = *(const bf16x8*)&H[(size_t)sA * DH + c0];
#pragma unroll
        for (int i = 0; i < 8; ++i) acc[i] += (float)vA[i] * cA;
    }
    float di = dinv[n], sc = di * di;
    bf16x8 vs = *(const bf16x8*)&H[(size_t)n * DH + c0];
#pragma unroll
    for (int i = 0; i < 8; ++i) acc[i] += (float)vs[i] * sc;
    f32x4 bb0 = *(const f32x4*)&bias[c0], bb1 = *(const f32x4*)&bias[c0 + 4];
#pragma unroll
    for (int i = 0; i < 4; ++i) {
        acc[i] = fmaxf(acc[i] + bb0[i], 0.f);
        acc[i + 4] = fmaxf(acc[i + 4] + bb1[i], 0.f);
    }
    bf16x8 o;
    if (DO_LN) {
        float s = 0.f, s2 = 0.f;
#pragma unroll
        for (int i = 0; i < 8; ++i) {
            s += acc[i];
            s2 += acc[i] * acc[i];
        }
#pragma unroll
        for (int off = 32; off; off >>= 1) {
            s += __shfl_xor(s, off);
            s2 += __shfl_xor(s2, off);
        }
        float mu = s * (1.f / 512.f);
        float var = s2 * (1.f / 512.f) - mu * mu;
        float r = rsqrtf(var + 1e-5f);
        f32x4 g0 = *(const f32x4*)&gamma[c0], g1 = *(const f32x4*)&gamma[c0 + 4];
        f32x4 be0 = *(const f32x4*)&beta[c0], be1 = *(const f32x4*)&beta[c0 + 4];
#pragma unroll
        for (int i = 0; i < 4; ++i) {
            o[i] = (bf16_t)((acc[i] - mu) * r * g0[i] + be0[i]);
            o[i + 4] = (bf16_t)((acc[i + 4] - mu) * r * g1[i] + be1[i]);
        }
    } else {
#pragma unroll
        for (int i = 0; i < 8; ++i) o[i] = (bf16_t)acc[i];
    }
    *(bf16x8*)&out[(size_t)n * DH + c0] = o;
}

// ---------------- fused mean-pool + final linear ----------------

__global__ __launch_bounds__(256) void k_poolfin(const bf16_t* __restrict__ h,
                                                 const int* __restrict__ batch,
                                                 const float* __restrict__ linW,
                                                 const float* __restrict__ linb,
                                                 float* __restrict__ out) {
    __shared__ float pooled[DH];
    __shared__ float red[256];
    int g = blockIdx.x;
    int t = threadIdx.x;
    int lo = 0, hi = NN;
    while (lo < hi) {
        int mid = (lo + hi) >> 1;
        if (batch[mid] < g) lo = mid + 1;
        else hi = mid;
    }
    int start = lo;
    hi = NN;
    while (lo < hi) {
        int mid = (lo + hi) >> 1;
        if (batch[mid] < g + 1) lo = mid + 1;
        else hi = mid;
    }
    int end = lo;
    int c0 = t * 2;
    float a0 = 0.f, a1 = 0.f;
    for (int i = start; i < end; ++i) {
        bf16x2 v = *(const bf16x2*)&h[(size_t)i * DH + c0];
        a0 += (float)v[0];
        a1 += (float)v[1];
    }
    float inv = 1.f / fmaxf((float)(end - start), 1.0f);
    pooled[c0] = a0 * inv;
    pooled[c0 + 1] = a1 * inv;
    __syncthreads();
    int o = t & 15, c = t >> 4;
    float s = 0.f;
    int k0 = c * 32;
    for (int k = k0; k < k0 + 32; ++k) s += pooled[k] * linW[k * DOUT + o];
    red[t] = s;
    __syncthreads();
    if (t < DOUT) {
        float acc2 = 0.f;
        for (int cc = 0; cc < 16; ++cc) acc2 += red[cc * 16 + t];
        out[g * DOUT + t] = acc2 + linb[t];
    }
}

// ---------------- launch ----------------

extern "C" void kernel_launch(void* const* d_in, const int* in_sizes, int n_in,
                              void* d_out, int out_size, void* d_ws, size_t ws_size,
                              hipStream_t stream) {
    const float* x = (const float*)d_in[0];
    const int* ei = (const int*)d_in[1];
    const int* batch = (const int*)d_in[2];
    const float* W0 = (const float*)d_in[3];
    const float* b0 = (const float*)d_in[4];
    const float* g0 = (const float*)d_in[5];
    const float* be0 = (const float*)d_in[6];
    const float* Wh = (const float*)d_in[7];
    const float* bh = (const float*)d_in[8];
    const float* gh = (const float*)d_in[9];
    const float* beh = (const float*)d_in[10];
    const float* linW = (const float*)d_in[11];
    const float* linb = (const float*)d_in[12];
    float* out = (float*)d_out;

    // workspace layout
    bf16_t* lnbuf = (bf16_t*)d_ws;                        // NPAD*512 bf16 (ln out / final h)
    bf16_t* Cbf = lnbuf + (size_t)NPAD * DH;              // NPAD*512 bf16 (gemm out)
    bf16_t* lnx = Cbf + (size_t)NPAD * DH;                // NPAD*128 (layer-0 LN out)
    bf16_t* aggx = lnx + (size_t)NPAD * DIN;              // NPAD*128 (layer-0 agg out)
    bf16_t* Wt0 = aggx + (size_t)NPAD * DIN;              // 512*128
    bf16_t* Wth = Wt0 + 512 * DIN;                        // 3*512*512
    float* dinv = (float*)(Wth + 3 * 512 * 512);          // N
    int* deg = (int*)(dinv + NN);
    int* rowptr = deg + NN;
    int* cursor = rowptr + NN + 1;
    int* csr_src = cursor + NN;
    float* csr_coef = (float*)(csr_src + NE);

    const int* srcp = ei;
    const int* dstp = ei + NE;

    hipMemsetAsync(deg, 0, NN * sizeof(int), stream);
    hipMemsetAsync(cursor, 0, NN * sizeof(int), stream);
    k_deg_count<<<(NE + 255) / 256, 256, 0, stream>>>(dstp, deg);
    k_dinv<<<(NN + 255) / 256, 256, 0, stream>>>(deg, dinv);
    k_scan<<<1, 1024, 0, stream>>>(deg, rowptr);
    k_fill_csr<<<(NE + 255) / 256, 256, 0, stream>>>(srcp, dstp, dinv, rowptr, cursor,
                                                     csr_src, csr_coef);
    k_wt_all<<<(512 * DIN + 3 * DH * DH + 255) / 256, 256, 0, stream>>>(W0, Wh, Wt0, Wth);

    dim3 gemm_grid(NPAD / 128, DH / 64);

    // layer 0: LN -> agg(128-wide) -> GEMM(+bias+relu) -> standalone LN for layer 1
    k_ln0<<<(NN + 3) / 4, 256, 0, stream>>>(x, g0, be0, lnx);
    k_agg128<<<NN / 4, 256, 0, stream>>>(lnx, rowptr, csr_src, csr_coef, dinv, aggx);
    k_gemm_bf16<true><<<gemm_grid, 256, 0, stream>>>(aggx, Wt0, b0, Cbf, DIN);
    k_ln512<<<(NN + 3) / 4, 256, 0, stream>>>(Cbf, gh + 0 * DH, beh + 0 * DH, lnbuf);

    // layers 1..2: GEMM -> agg(+bias+relu+LN)
    for (int l = 0; l < 2; ++l) {
        k_gemm_bf16<false><<<gemm_grid, 256, 0, stream>>>(lnbuf, Wth + (size_t)l * DH * DH,
                                                          nullptr, Cbf, DH);
        k_agg<true><<<NN / 4, 256, 0, stream>>>(Cbf, rowptr, csr_src, csr_coef, dinv,
                                                bh + l * DH, gh + (l + 1) * DH,
                                                beh + (l + 1) * DH, lnbuf);
    }
    // layer 3: GEMM -> agg(+bias+relu), bf16 out into lnbuf
    k_gemm_bf16<false><<<gemm_grid, 256, 0, stream>>>(lnbuf, Wth + (size_t)2 * DH * DH,
                                                      nullptr, Cbf, DH);
    k_agg<false><<<NN / 4, 256, 0, stream>>>(Cbf, rowptr, csr_src, csr_coef, dinv,
                                             bh + 2 * DH, nullptr, nullptr, lnbuf);

    k_poolfin<<<NG, 256, 0, stream>>>(lnbuf, batch, linW, linb, out);
}

// Round 4
// 207.411 us; speedup vs baseline: 2.6433x; 1.1348x over previous
//
#include <hip/hip_runtime.h>

#define NN 10000
#define NE 160000
#define NG 512
#define DIN 128
#define DH 512
#define DOUT 16
#define NPAD 10112   // 158 * 64 (GEMM M-tile padding)

typedef __bf16 bf16_t;
typedef __attribute__((ext_vector_type(8))) __bf16 bf16x8;
typedef __attribute__((ext_vector_type(2))) __bf16 bf16x2;
typedef __attribute__((ext_vector_type(4))) float f32x4;
typedef __attribute__((ext_vector_type(2))) float f32x2;

// k_prep block ranges
#define LNB 2500                        // ln0: 4 rows/block
#define DEGB ((NE + 255) / 256)         // 625
#define WTE (512 * DIN + 3 * DH * DH)   // 851968
#define WTB ((WTE + 255) / 256)         // 3328
#define CURB ((NN + 255) / 256)         // 40

// ---------------- fused prep: ln0 + degree count + weight convert + cursor zero ----------------

__global__ __launch_bounds__(256) void k_prep(const float* __restrict__ x,
                                              const float* __restrict__ g0,
                                              const float* __restrict__ be0,
                                              bf16_t* __restrict__ lnx,
                                              const int* __restrict__ dst,
                                              int* __restrict__ deg,
                                              const float* __restrict__ W0,
                                              const float* __restrict__ Wh,
                                              bf16_t* __restrict__ Wt0,
                                              bf16_t* __restrict__ Wth,
                                              int* __restrict__ cursor) {
    int b = blockIdx.x;
    int tid = threadIdx.x;
    if (b < LNB) {
        int row = b * 4 + (tid >> 6);
        int lane = tid & 63;
        const float* xr = x + (size_t)row * DIN;
        float v0 = xr[lane], v1 = xr[lane + 64];
        float s = v0 + v1, s2 = v0 * v0 + v1 * v1;
#pragma unroll
        for (int off = 32; off; off >>= 1) {
            s += __shfl_xor(s, off);
            s2 += __shfl_xor(s2, off);
        }
        float mu = s * (1.f / 128.f);
        float var = s2 * (1.f / 128.f) - mu * mu;
        float r = rsqrtf(var + 1e-5f);
        bf16_t* yr = lnx + (size_t)row * DIN;
        yr[lane] = (bf16_t)((v0 - mu) * r * g0[lane] + be0[lane]);
        yr[lane + 64] = (bf16_t)((v1 - mu) * r * g0[lane + 64] + be0[lane + 64]);
    } else if (b < LNB + DEGB) {
        int e = (b - LNB) * 256 + tid;
        if (e < NE) atomicAdd(&deg[dst[e]], 1);
    } else if (b < LNB + DEGB + WTB) {
        int idx = (b - LNB - DEGB) * 256 + tid;
        if (idx < 512 * DIN) {
            int k = idx >> 9, n = idx & 511;   // W0 is [128][512]
            Wt0[n * DIN + k] = (bf16_t)W0[idx];
        } else if (idx < WTE) {
            int j = idx - 512 * DIN;
            int l = j >> 18;                   // / (512*512)
            int r2 = j & 262143;
            int k = r2 >> 9, n = r2 & 511;     // Wh[l] is [512][512]
            Wth[((size_t)l << 18) + n * DH + k] = (bf16_t)Wh[j];
        }
    } else {
        int i = (b - LNB - DEGB - WTB) * 256 + tid;
        if (i < NN) cursor[i] = 0;
    }
}

// ---------------- scan (rowptr) + dinv ----------------

__global__ __launch_bounds__(1024) void k_scan(const int* __restrict__ cnt,
                                               int* __restrict__ rowptr,
                                               float* __restrict__ dinv) {
    __shared__ int part[1024];
    int tid = threadIdx.x;
    const int PER = 10;
    int base = tid * PER;
    int local[PER];
    int s = 0;
#pragma unroll
    for (int i = 0; i < PER; ++i) {
        int idx = base + i;
        int v = (idx < NN) ? cnt[idx] : 0;
        if (idx < NN) dinv[idx] = rsqrtf((float)v + 1.0f);
        local[i] = s;
        s += v;
    }
    part[tid] = s;
    __syncthreads();
    for (int off = 1; off < 1024; off <<= 1) {
        int v = (tid >= off) ? part[tid - off] : 0;
        __syncthreads();
        part[tid] += v;
        __syncthreads();
    }
    int offset = (tid > 0) ? part[tid - 1] : 0;
#pragma unroll
    for (int i = 0; i < PER; ++i) {
        int idx = base + i;
        if (idx < NN) rowptr[idx] = offset + local[i];
    }
    if (tid == 1023) rowptr[NN] = part[1023];
}

__global__ void k_fill_csr(const int* __restrict__ src, const int* __restrict__ dst,
                           const float* __restrict__ dinv, const int* __restrict__ rowptr,
                           int* __restrict__ cursor, int2* __restrict__ csr) {
    int e = blockIdx.x * blockDim.x + threadIdx.x;
    if (e >= NE) return;
    int s = src[e], d = dst[e];
    int pos = atomicAdd(&cursor[d], 1);
    csr[rowptr[d] + pos] = make_int2(s, __float_as_int(dinv[s] * dinv[d]));
}

// ---------------- standalone layernorm 512-wide bf16 -> bf16 ----------------

__global__ __launch_bounds__(256) void k_ln512(const bf16_t* __restrict__ x,
                                               const float* __restrict__ g,
                                               const float* __restrict__ b,
                                               bf16_t* __restrict__ y) {
    int row = blockIdx.x * 4 + (threadIdx.x >> 6);
    int lane = threadIdx.x & 63;
    if (row >= NN) return;
    int c0 = lane * 8;
    bf16x8 v = *(const bf16x8*)&x[(size_t)row * DH + c0];
    float f[8];
    float s = 0.f, s2 = 0.f;
#pragma unroll
    for (int i = 0; i < 8; ++i) {
        f[i] = (float)v[i];
        s += f[i];
        s2 += f[i] * f[i];
    }
#pragma unroll
    for (int off = 32; off; off >>= 1) {
        s += __shfl_xor(s, off);
        s2 += __shfl_xor(s2, off);
    }
    float mu = s * (1.f / 512.f);
    float var = s2 * (1.f / 512.f) - mu * mu;
    float r = rsqrtf(var + 1e-5f);
    f32x4 g0 = *(const f32x4*)&g[c0], g1 = *(const f32x4*)&g[c0 + 4];
    f32x4 b0 = *(const f32x4*)&b[c0], b1 = *(const f32x4*)&b[c0 + 4];
    bf16x8 o;
#pragma unroll
    for (int i = 0; i < 4; ++i) {
        o[i] = (bf16_t)((f[i] - mu) * r * g0[i] + b0[i]);
        o[i + 4] = (bf16_t)((f[i + 4] - mu) * r * g1[i] + b1[i]);
    }
    *(bf16x8*)&y[(size_t)row * DH + c0] = o;
}

// ---------------- bf16 MFMA GEMM: BM=64 BN=64 BK=64, 4 waves each 32x32 ----------------
// Wt is [512][K]; LDS XOR chunk swizzle (chunk ^= row&7), pre-swizzled global source.

template <bool EPI>
__global__ __launch_bounds__(256) void k_gemm64(const bf16_t* __restrict__ A,
                                                const bf16_t* __restrict__ Bt,
                                                const float* __restrict__ bias,
                                                bf16_t* __restrict__ C, int K) {
    __shared__ bf16_t As[64 * 64];
    __shared__ bf16_t Bs[64 * 64];
    int tid = threadIdx.x;
    int lane = tid & 63, w = tid >> 6;
    int row0 = blockIdx.x * 64, col0 = blockIdx.y * 64;
    int wm = w >> 1, wn = w & 1;

    f32x4 acc[2][2];
#pragma unroll
    for (int i = 0; i < 2; ++i)
#pragma unroll
        for (int j = 0; j < 2; ++j) acc[i][j] = (f32x4){0.f, 0.f, 0.f, 0.f};

    int lr = lane >> 3;
    int lc = lane & 7;

    for (int kt = 0; kt < K; kt += 64) {
#pragma unroll
        for (int i = 0; i < 2; ++i) {
            int r = w * 16 + i * 8 + lr;
            int cg = lc ^ (r & 7);
            const bf16_t* srca = A + (size_t)(row0 + r) * K + kt + cg * 8;
            __builtin_amdgcn_global_load_lds(
                (const __attribute__((address_space(1))) void*)srca,
                (__attribute__((address_space(3))) void*)(As + (w * 16 + i * 8) * 64),
                16, 0, 0);
            const bf16_t* srcb = Bt + (size_t)(col0 + r) * K + kt + cg * 8;
            __builtin_amdgcn_global_load_lds(
                (const __attribute__((address_space(1))) void*)srcb,
                (__attribute__((address_space(3))) void*)(Bs + (w * 16 + i * 8) * 64),
                16, 0, 0);
        }
        __syncthreads();
#pragma unroll
        for (int ks = 0; ks < 2; ++ks) {
            bf16x8 af[2], bfr[2];
#pragma unroll
            for (int mi = 0; mi < 2; ++mi) {
                int mr = wm * 32 + mi * 16 + (lane & 15);
                int c = (ks * 4 + (lane >> 4)) ^ (mr & 7);
                af[mi] = *(const bf16x8*)&As[mr * 64 + c * 8];
            }
#pragma unroll
            for (int ni = 0; ni < 2; ++ni) {
                int nr = wn * 32 + ni * 16 + (lane & 15);
                int c = (ks * 4 + (lane >> 4)) ^ (nr & 7);
                bfr[ni] = *(const bf16x8*)&Bs[nr * 64 + c * 8];
            }
#pragma unroll
            for (int mi = 0; mi < 2; ++mi)
#pragma unroll
                for (int ni = 0; ni < 2; ++ni)
                    acc[mi][ni] = __builtin_amdgcn_mfma_f32_16x16x32_bf16(
                        af[mi], bfr[ni], acc[mi][ni], 0, 0, 0);
        }
        __syncthreads();
    }
#pragma unroll
    for (int mi = 0; mi < 2; ++mi)
#pragma unroll
        for (int ni = 0; ni < 2; ++ni) {
            int col = col0 + wn * 32 + ni * 16 + (lane & 15);
            float bv = EPI ? bias[col] : 0.f;
#pragma unroll
            for (int q = 0; q < 4; ++q) {
                int row = row0 + wm * 32 + mi * 16 + (lane >> 4) * 4 + q;
                float v = acc[mi][ni][q];
                if (EPI) v = fmaxf(v + bv, 0.f);
                C[(size_t)row * DH + col] = (bf16_t)v;
            }
        }
}

// ---------------- layer-0 aggregate, 128-wide, block per node (4-wave edge split) ----------------

__global__ __launch_bounds__(256) void k_agg128(const bf16_t* __restrict__ H,
                                                const int* __restrict__ rowptr,
                                                const int2* __restrict__ csr,
                                                const float* __restrict__ dinv,
                                                bf16_t* __restrict__ out) {
    __shared__ float part[4][DIN];
    int n = blockIdx.x;
    int w = threadIdx.x >> 6, lane = threadIdx.x & 63;
    int c0 = lane * 2;
    float a0 = 0.f, a1 = 0.f;
    int s0 = rowptr[n], s1 = rowptr[n + 1];
    int k = s0 + w;
    for (; k + 4 < s1; k += 8) {
        int2 eA = csr[k], eB = csr[k + 4];
        float cA = __int_as_float(eA.y), cB = __int_as_float(eB.y);
        bf16x2 vA = *(const bf16x2*)&H[(size_t)eA.x * DIN + c0];
        bf16x2 vB = *(const bf16x2*)&H[(size_t)eB.x * DIN + c0];
        a0 += (float)vA[0] * cA + (float)vB[0] * cB;
        a1 += (float)vA[1] * cA + (float)vB[1] * cB;
    }
    if (k < s1) {
        int2 eA = csr[k];
        float cA = __int_as_float(eA.y);
        bf16x2 vA = *(const bf16x2*)&H[(size_t)eA.x * DIN + c0];
        a0 += (float)vA[0] * cA;
        a1 += (float)vA[1] * cA;
    }
    part[w][c0] = a0;
    part[w][c0 + 1] = a1;
    __syncthreads();
    if (threadIdx.x < 64) {
        int cc = threadIdx.x * 2;
        float b0 = part[0][cc] + part[1][cc] + part[2][cc] + part[3][cc];
        float b1 = part[0][cc + 1] + part[1][cc + 1] + part[2][cc + 1] + part[3][cc + 1];
        float di = dinv[n], sc = di * di;
        bf16x2 vs = *(const bf16x2*)&H[(size_t)n * DIN + cc];
        b0 += (float)vs[0] * sc;
        b1 += (float)vs[1] * sc;
        bf16x2 o;
        o[0] = (bf16_t)b0;
        o[1] = (bf16_t)b1;
        *(bf16x2*)&out[(size_t)n * DIN + cc] = o;
    }
}

// ---------------- 512-wide aggregate + bias + relu (+ LN), block per node ----------------

template <bool DO_LN>
__global__ __launch_bounds__(256) void k_agg(const bf16_t* __restrict__ H,
                                             const int* __restrict__ rowptr,
                                             const int2* __restrict__ csr,
                                             const float* __restrict__ dinv,
                                             const float* __restrict__ bias,
                                             const float* __restrict__ gamma,
                                             const float* __restrict__ beta,
                                             bf16_t* __restrict__ out) {
    __shared__ float part[4][DH];
    __shared__ float rs[8];
    int n = blockIdx.x;
    int w = threadIdx.x >> 6, lane = threadIdx.x & 63;
    int c0 = lane * 8;
    float acc[8] = {0.f, 0.f, 0.f, 0.f, 0.f, 0.f, 0.f, 0.f};
    int s0 = rowptr[n], s1 = rowptr[n + 1];
    int k = s0 + w;
    for (; k + 4 < s1; k += 8) {
        int2 eA = csr[k], eB = csr[k + 4];
        float cA = __int_as_float(eA.y), cB = __int_as_float(eB.y);
        bf16x8 vA = *(const bf16x8*)&H[(size_t)eA.x * DH + c0];
        bf16x8 vB = *(const bf16x8*)&H[(size_t)eB.x * DH + c0];
#pragma unroll
        for (int i = 0; i < 8; ++i) acc[i] += (float)vA[i] * cA + (float)vB[i] * cB;
    }
    if (k < s1) {
        int2 eA = csr[k];
        float cA = __int_as_float(eA.y);
        bf16x8 vA = *(const bf16x8*)&H[(size_t)eA.x * DH + c0];
#pragma unroll
        for (int i = 0; i < 8; ++i) acc[i] += (float)vA[i] * cA;
    }
    *(f32x4*)&part[w][c0] = (f32x4){acc[0], acc[1], acc[2], acc[3]};
    *(f32x4*)&part[w][c0 + 4] = (f32x4){acc[4], acc[5], acc[6], acc[7]};
    __syncthreads();
    int cc = threadIdx.x * 2;
    f32x2 p0 = *(const f32x2*)&part[0][cc];
    f32x2 p1 = *(const f32x2*)&part[1][cc];
    f32x2 p2 = *(const f32x2*)&part[2][cc];
    f32x2 p3 = *(const f32x2*)&part[3][cc];
    float a0 = p0[0] + p1[0] + p2[0] + p3[0];
    float a1 = p0[1] + p1[1] + p2[1] + p3[1];
    float di = dinv[n], sc = di * di;
    bf16x2 vs = *(const bf16x2*)&H[(size_t)n * DH + cc];
    a0 += (float)vs[0] * sc;
    a1 += (float)vs[1] * sc;
    a0 = fmaxf(a0 + bias[cc], 0.f);
    a1 = fmaxf(a1 + bias[cc + 1], 0.f);
    bf16x2 o;
    if (DO_LN) {
        float s = a0 + a1, s2 = a0 * a0 + a1 * a1;
#pragma unroll
        for (int off = 32; off; off >>= 1) {
            s += __shfl_xor(s, off);
            s2 += __shfl_xor(s2, off);
        }
        if (lane == 0) {
            rs[w] = s;
            rs[4 + w] = s2;
        }
        __syncthreads();
        s = rs[0] + rs[1] + rs[2] + rs[3];
        s2 = rs[4] + rs[5] + rs[6] + rs[7];
        float mu = s * (1.f / 512.f);
        float var = s2 * (1.f / 512.f) - mu * mu;
        float r = rsqrtf(var + 1e-5f);
        o[0] = (bf16_t)((a0 - mu) * r * gamma[cc] + beta[cc]);
        o[1] = (bf16_t)((a1 - mu) * r * gamma[cc + 1] + beta[cc + 1]);
    } else {
        o[0] = (bf16_t)a0;
        o[1] = (bf16_t)a1;
    }
    *(bf16x2*)&out[(size_t)n * DH + cc] = o;
}

// ---------------- fused mean-pool + final linear ----------------

__global__ __launch_bounds__(256) void k_poolfin(const bf16_t* __restrict__ h,
                                                 const int* __restrict__ batch,
                                                 const float* __restrict__ linW,
                                                 const float* __restrict__ linb,
                                                 float* __restrict__ out) {
    __shared__ float pooled[DH];
    __shared__ float red[256];
    int g = blockIdx.x;
    int t = threadIdx.x;
    int lo = 0, hi = NN;
    while (lo < hi) {
        int mid = (lo + hi) >> 1;
        if (batch[mid] < g) lo = mid + 1;
        else hi = mid;
    }
    int start = lo;
    hi = NN;
    while (lo < hi) {
        int mid = (lo + hi) >> 1;
        if (batch[mid] < g + 1) lo = mid + 1;
        else hi = mid;
    }
    int end = lo;
    int c0 = t * 2;
    float a0 = 0.f, a1 = 0.f;
    for (int i = start; i < end; ++i) {
        bf16x2 v = *(const bf16x2*)&h[(size_t)i * DH + c0];
        a0 += (float)v[0];
        a1 += (float)v[1];
    }
    float inv = 1.f / fmaxf((float)(end - start), 1.0f);
    pooled[c0] = a0 * inv;
    pooled[c0 + 1] = a1 * inv;
    __syncthreads();
    int o = t & 15, c = t >> 4;
    float s = 0.f;
    int k0 = c * 32;
    for (int k = k0; k < k0 + 32; ++k) s += pooled[k] * linW[k * DOUT + o];
    red[t] = s;
    __syncthreads();
    if (t < DOUT) {
        float acc2 = 0.f;
        for (int cc = 0; cc < 16; ++cc) acc2 += red[cc * 16 + t];
        out[g * DOUT + t] = acc2 + linb[t];
    }
}

// ---------------- launch ----------------

extern "C" void kernel_launch(void* const* d_in, const int* in_sizes, int n_in,
                              void* d_out, int out_size, void* d_ws, size_t ws_size,
                              hipStream_t stream) {
    const float* x = (const float*)d_in[0];
    const int* ei = (const int*)d_in[1];
    const int* batch = (const int*)d_in[2];
    const float* W0 = (const float*)d_in[3];
    const float* b0 = (const float*)d_in[4];
    const float* g0 = (const float*)d_in[5];
    const float* be0 = (const float*)d_in[6];
    const float* Wh = (const float*)d_in[7];
    const float* bh = (const float*)d_in[8];
    const float* gh = (const float*)d_in[9];
    const float* beh = (const float*)d_in[10];
    const float* linW = (const float*)d_in[11];
    const float* linb = (const float*)d_in[12];
    float* out = (float*)d_out;

    // workspace layout
    bf16_t* lnbuf = (bf16_t*)d_ws;                        // NPAD*512 (ln out / final h)
    bf16_t* Cbf = lnbuf + (size_t)NPAD * DH;              // NPAD*512 (gemm out)
    bf16_t* lnx = Cbf + (size_t)NPAD * DH;                // NPAD*128 (layer-0 LN out)
    bf16_t* aggx = lnx + (size_t)NPAD * DIN;              // NPAD*128 (layer-0 agg out)
    bf16_t* Wt0 = aggx + (size_t)NPAD * DIN;              // 512*128
    bf16_t* Wth = Wt0 + 512 * DIN;                        // 3*512*512
    float* dinv = (float*)(Wth + 3 * DH * DH);            // N
    int* deg = (int*)(dinv + NN);                         // N
    int* rowptr = deg + NN;                               // N+1
    int* cursor = rowptr + NN + 1;                        // N (+1 pad for int2 align)
    int2* csr = (int2*)(cursor + NN + 1);                 // E

    const int* srcp = ei;
    const int* dstp = ei + NE;

    hipMemsetAsync(deg, 0, NN * sizeof(int), stream);
    k_prep<<<LNB + DEGB + WTB + CURB, 256, 0, stream>>>(x, g0, be0, lnx, dstp, deg,
                                                        W0, Wh, Wt0, Wth, cursor);
    k_scan<<<1, 1024, 0, stream>>>(deg, rowptr, dinv);
    k_fill_csr<<<(NE + 255) / 256, 256, 0, stream>>>(srcp, dstp, dinv, rowptr, cursor, csr);

    dim3 gemm_grid(NPAD / 64, DH / 64);

    // layer 0: agg(128-wide) -> GEMM(+bias+relu) -> LN for layer 1
    k_agg128<<<NN, 256, 0, stream>>>(lnx, rowptr, csr, dinv, aggx);
    k_gemm64<true><<<gemm_grid, 256, 0, stream>>>(aggx, Wt0, b0, Cbf, DIN);
    k_ln512<<<(NN + 3) / 4, 256, 0, stream>>>(Cbf, gh + 0 * DH, beh + 0 * DH, lnbuf);

    // layers 1..2: GEMM -> agg(+bias+relu+LN)
    for (int l = 0; l < 2; ++l) {
        k_gemm64<false><<<gemm_grid, 256, 0, stream>>>(lnbuf, Wth + (size_t)l * DH * DH,
                                                       nullptr, Cbf, DH);
        k_agg<true><<<NN, 256, 0, stream>>>(Cbf, rowptr, csr, dinv, bh + l * DH,
                                            gh + (l + 1) * DH, beh + (l + 1) * DH, lnbuf);
    }
    // layer 3: GEMM -> agg(+bias+relu), bf16 out
    k_gemm64<false><<<gemm_grid, 256, 0, stream>>>(lnbuf, Wth + (size_t)2 * DH * DH,
                                                   nullptr, Cbf, DH);
    k_agg<false><<<NN, 256, 0, stream>>>(Cbf, rowptr, csr, dinv, bh + 2 * DH,
                                         nullptr, nullptr, lnbuf);

    k_poolfin<<<NG, 256, 0, stream>>>(lnbuf, batch, linW, linb, out);
}